// Round 3
// baseline (5920.097 us; speedup 1.0000x reference)
//
#include <hip/hip_runtime.h>
#include <hip/hip_bf16.h>
#include <math.h>

// InstructPerceiverResampler on MI355X (gfx950).
// Round 3: big flat GEMMs moved to a 256x256 8-phase kernel (gemm256):
//   512 thr (8 waves 2x4), BK=64, 128KiB dbuf LDS, raw s_barrier + counted
//   vmcnt(4) (never 0 in-loop), XOR swizzle blk^=(row&7) both-sides
//   (pre-swizzled global source + swizzled ds_read), setprio around MFMA,
//   XCD-bijective block swizzle. Staging order [Blo,Bhi,Alo,Ahi], lookahead 6.
// Small/batched GEMMs stay on the verified 128^2 2-phase gemm_t.

typedef __attribute__((ext_vector_type(4))) float f32x4;
typedef __attribute__((ext_vector_type(8))) short bf16x8;
typedef unsigned int u32;

#define DEV __device__ __forceinline__

DEV float bf2f(short s){ union{u32 u; float f;} v; v.u = ((u32)(unsigned short)s) << 16; return v.f; }
DEV short f2bf(float f){
  union{float f; u32 u;} v; v.f = f;
  u32 r = (v.u + 0x7FFFu + ((v.u >> 16) & 1u)) >> 16;
  return (short)r;
}

// ---------------------------------------------------------------------------
// 256x256 8-phase GEMM: C[m,n] = A[m,k]*B[n,k] (+bias)(+gelu), bf16 in/out.
// CMAP 0: C[gm*ldc+gn]
// CMAP 1: (kv x-part)  C[(gm/729*857 + gm%729)*3072 + gn]
// CMAP 2: (fused q|kv) gn<1536 -> C[gm*1536+gn]*SCALE ; else
//                      C2[((gm>>7)*857+729+(gm&127))*3072 + gn-1536]
// ---------------------------------------------------------------------------
template<int GELU, int BIAS, int CMAP>
__global__ __launch_bounds__(512, 2)
void gemm256(const short* __restrict__ A, const short* __restrict__ Bm,
             short* __restrict__ C, short* __restrict__ C2,
             const float* __restrict__ bias,
             int K, int lda, int ldb, int ldc,
             int Mvalid, int NBmax, int Nwrite)
{
  __shared__ __align__(16) short LDS[65536];   // 128 KiB: [buf][A(16384)|B(16384)]

  // XCD-aware bijective block swizzle (grid sizes here are %8==0 or guarded)
  int nwg = gridDim.x * gridDim.y;
  int bid = blockIdx.y * gridDim.x + blockIdx.x;
  if ((nwg & 7) == 0){
    int chunk = nwg >> 3;
    bid = (bid & 7) * chunk + (bid >> 3);
  }
  int by = bid / gridDim.x;
  int m0 = by * 256;
  int n0 = (bid - by * gridDim.x) * 256;

  int tid = threadIdx.x;
  int lane = tid & 63;
  int w = tid >> 6;           // 0..7
  int wr = w >> 2, wc = w & 3;

  // stage constants: lane -> row-in-8 (sl), phys 16B-block (sb); source block
  // is sb^sl (XOR swizzle is an involution; gload_lds dest stays linear).
  int sl = lane >> 3;
  int scol = ((lane & 7) ^ sl) * 8;     // shorts
  int r0 = w*8 + sl;
  int r1 = 64 + w*8 + sl;

  // reader constants
  int rsel = lane & 15;
  int g4 = lane >> 4;
  int xr = rsel & 7;
  int blk0 = (g4 ^ xr) * 8;             // ks=0 swizzled block offset (shorts)
  int blk1 = ((4 + g4) ^ xr) * 8;       // ks=1
  int aoff = (wr*128 + rsel)*64;
  int boff = 16384 + (wc*64 + rsel)*64;

  int nt = K >> 6;
  int H = nt << 2;

  f32x4 acc[8][4];
#pragma unroll
  for (int i=0;i<8;i++)
#pragma unroll
    for (int j=0;j<4;j++) acc[i][j] = (f32x4){0.f,0.f,0.f,0.f};

  auto stage = [&](int h){
    int tau = h >> 2;
    int reg = h & 3;                    // 0 Blo, 1 Bhi, 2 Alo, 3 Ahi
    int kb = tau << 6;
    int sbase = (tau & 1)*32768 + ((reg & 2) ? 0 : 16384) + (reg & 1)*8192;
    char* l0 = (char*)LDS + sbase*2 + (w*8)*128;
    char* l1 = (char*)LDS + sbase*2 + (64 + w*8)*128;
    if (reg & 2){
      int ra0 = m0 + (reg&1)*128 + r0; if (ra0 >= Mvalid) ra0 = Mvalid-1;
      int ra1 = m0 + (reg&1)*128 + r1; if (ra1 >= Mvalid) ra1 = Mvalid-1;
      const short* g0 = A + (long)ra0*lda + kb + scol;
      const short* g1 = A + (long)ra1*lda + kb + scol;
      __builtin_amdgcn_global_load_lds((const __attribute__((address_space(1))) u32*)g0,
          (__attribute__((address_space(3))) u32*)l0, 16, 0, 0);
      __builtin_amdgcn_global_load_lds((const __attribute__((address_space(1))) u32*)g1,
          (__attribute__((address_space(3))) u32*)l1, 16, 0, 0);
    } else {
      int rb0 = n0 + (reg&1)*128 + r0; if (rb0 >= NBmax) rb0 = NBmax-1;
      int rb1 = n0 + (reg&1)*128 + r1; if (rb1 >= NBmax) rb1 = NBmax-1;
      const short* g0 = Bm + (long)rb0*ldb + kb + scol;
      const short* g1 = Bm + (long)rb1*ldb + kb + scol;
      __builtin_amdgcn_global_load_lds((const __attribute__((address_space(1))) u32*)g0,
          (__attribute__((address_space(3))) u32*)l0, 16, 0, 0);
      __builtin_amdgcn_global_load_lds((const __attribute__((address_space(1))) u32*)g1,
          (__attribute__((address_space(3))) u32*)l1, 16, 0, 0);
    }
  };

  bf16x8 a0[4], a1[4], b0[4], b1[4];
  auto ldA = [&](bf16x8* a, int mh, int blk, int bufs){
#pragma unroll
    for (int m=0;m<4;m++)
      a[m] = *(const bf16x8*)&LDS[bufs + aoff + (mh*64 + m*16)*64 + blk];
  };
  auto ldB = [&](bf16x8* bq, int blk, int bufs){
#pragma unroll
    for (int n=0;n<4;n++)
      bq[n] = *(const bf16x8*)&LDS[bufs + boff + (n*16)*64 + blk];
  };
  auto mm = [&](bf16x8* a, bf16x8* bq, int mh){
#pragma unroll
    for (int m=0;m<4;m++)
#pragma unroll
      for (int n=0;n<4;n++)
        acc[mh*4+m][n] = __builtin_amdgcn_mfma_f32_16x16x32_bf16(a[m], bq[n], acc[mh*4+m][n], 0, 0, 0);
  };

#define PHASE_MID() \
    asm volatile("s_barrier" ::: "memory"); \
    __builtin_amdgcn_sched_barrier(0); \
    __builtin_amdgcn_s_setprio(1)
#define PHASE_END() \
    __builtin_amdgcn_s_setprio(0); \
    __builtin_amdgcn_sched_barrier(0); \
    asm volatile("s_barrier" ::: "memory")

  // prologue: tile0 (4 half-tiles) + tile1's Blo,Bhi
#pragma unroll 1
  for (int h=0; h<6; ++h) stage(h);

#pragma unroll 1
  for (int t=0; t<nt; ++t){
    int bufs = (t & 1) * 32768;
    if (t == nt-1) { asm volatile("s_waitcnt vmcnt(0)" ::: "memory"); }
    else           { asm volatile("s_waitcnt vmcnt(4)" ::: "memory"); }
    asm volatile("s_barrier" ::: "memory");
    int h0 = 6 + 4*t;
    // P0: quadrant (mh=0, ks=0)
    ldA(a0, 0, blk0, bufs); ldB(b0, blk0, bufs);
    if (h0 < H) stage(h0);
    PHASE_MID(); mm(a0, b0, 0); PHASE_END();
    // P1: (mh=0, ks=1)
    ldA(a1, 0, blk1, bufs); ldB(b1, blk1, bufs);
    if (h0+1 < H) stage(h0+1);
    PHASE_MID(); mm(a1, b1, 0); PHASE_END();
    // P2: (mh=1, ks=0)  (b0 held in regs; B LDS region free after P1)
    ldA(a0, 1, blk0, bufs);
    if (h0+2 < H) stage(h0+2);
    PHASE_MID(); mm(a0, b0, 1); PHASE_END();
    // P3: (mh=1, ks=1)
    ldA(a1, 1, blk1, bufs);
    if (h0+3 < H) stage(h0+3);
    PHASE_MID(); mm(a1, b1, 1); PHASE_END();
  }
#undef PHASE_MID
#undef PHASE_END

  // epilogue: C/D frag layout col=lane&15, row=(lane>>4)*4+j
  int cq = (lane >> 4) * 4;
  int csel = lane & 15;
#pragma unroll
  for (int mi=0; mi<8; mi++){
#pragma unroll
    for (int n=0; n<4; n++){
#pragma unroll
      for (int j=0; j<4; j++){
        int gm = m0 + wr*128 + mi*16 + cq + j;
        int gn = n0 + wc*64 + n*16 + csel;
        if (gm < Mvalid && gn < Nwrite){
          float v = acc[mi][n][j];
          if (BIAS) v += bias[gn];
          if (GELU) v = 0.5f*v*(1.0f + erff(v*0.70710678118654752f));
          if (CMAP == 0){
            C[(long)gm*ldc + gn] = f2bf(v);
          } else if (CMAP == 1){
            int bb = gm / 729;
            int jj = gm - bb*729;
            C[((long)bb*857 + jj)*3072 + gn] = f2bf(v);
          } else {
            if (gn < 1536){
              C[(long)gm*1536 + gn] = f2bf(v * 0.1020620726159657f);
            } else {
              int bb = gm >> 7, jj = gm & 127;
              C2[((long)bb*857 + 729 + jj)*3072 + (gn - 1536)] = f2bf(v);
            }
          }
        }
      }
    }
  }
}

// ---------------------------------------------------------------------------
// 128x128 2-phase GEMM (verified r2) for small/batched shapes.
// ---------------------------------------------------------------------------
template<int GELU, int BIAS, int RES, int OUTF32>
__global__ __launch_bounds__(256)
void gemm_t(const short* __restrict__ A, const short* __restrict__ B,
            void* __restrict__ C, const float* __restrict__ bias,
            const float* __restrict__ res,
            int K, int lda, int ldb, int ldc,
            int Mvalid, int NBmax, int Nwrite,
            int zdiv, long sA1, long sA2, long sB1, long sB2, long sC1, long sC2,
            float scale)
{
  __shared__ __align__(16) short As[2][128*32];
  __shared__ __align__(16) short Bs[2][128*32];

  int z = blockIdx.z;
  int zq = z / zdiv, zr = z - zq*zdiv;
  const short* Ab = A + zq*sA1 + zr*sA2;
  const short* Bb = B + zq*sB1 + zr*sB2;
  long cOff = zq*sC1 + zr*sC2;
  int m0 = blockIdx.y * 128;
  int n0 = blockIdx.x * 128;
  int tid = threadIdx.x;
  int lane = tid & 63;
  int w = tid >> 6;
  int wm = (w >> 1) * 64, wn = (w & 1) * 64;

  int sr = lane >> 2;
  int sc = (lane & 3) * 8;
  int ar0 = m0 + w*32 + sr;
  int br0 = n0 + w*32 + sr;

  int raA0 = ar0;      if (raA0 > Mvalid-1) raA0 = Mvalid-1;
  int raA1 = ar0 + 16; if (raA1 > Mvalid-1) raA1 = Mvalid-1;
  int rbB0 = br0;      if (rbB0 > NBmax-1) rbB0 = NBmax-1;
  int rbB1 = br0 + 16; if (rbB1 > NBmax-1) rbB1 = NBmax-1;
  const short* gA0 = Ab + (long)raA0*lda + sc;
  const short* gA1 = Ab + (long)raA1*lda + sc;
  const short* gB0 = Bb + (long)rbB0*ldb + sc;
  const short* gB1 = Bb + (long)rbB1*ldb + sc;
  int ldsRow0 = (w*32)*32;
  int ldsRow1 = (w*32 + 16)*32;

  f32x4 acc[4][4];
#pragma unroll
  for (int i=0;i<4;i++)
#pragma unroll
    for (int j=0;j<4;j++) acc[i][j] = (f32x4){0.f,0.f,0.f,0.f};

  auto stage = [&](int buf, int kb){
    __builtin_amdgcn_global_load_lds(
        (const __attribute__((address_space(1))) u32*)(gA0 + kb),
        (__attribute__((address_space(3))) u32*)(&As[buf][ldsRow0]), 16, 0, 0);
    __builtin_amdgcn_global_load_lds(
        (const __attribute__((address_space(1))) u32*)(gA1 + kb),
        (__attribute__((address_space(3))) u32*)(&As[buf][ldsRow1]), 16, 0, 0);
    __builtin_amdgcn_global_load_lds(
        (const __attribute__((address_space(1))) u32*)(gB0 + kb),
        (__attribute__((address_space(3))) u32*)(&Bs[buf][ldsRow0]), 16, 0, 0);
    __builtin_amdgcn_global_load_lds(
        (const __attribute__((address_space(1))) u32*)(gB1 + kb),
        (__attribute__((address_space(3))) u32*)(&Bs[buf][ldsRow1]), 16, 0, 0);
  };

  int nt = K >> 5;
  stage(0, 0);
  __syncthreads();

  int kq = (lane >> 4) * 8;
  int rsel = lane & 15;
  int cur = 0;
  for (int t = 0; t < nt; ++t){
    if (t + 1 < nt) stage(cur ^ 1, (t+1)*32);

    bf16x8 af[4], bfr[4];
#pragma unroll
    for (int m=0;m<4;m++) af[m]  = *(const bf16x8*)&As[cur][(wm + m*16 + rsel)*32 + kq];
#pragma unroll
    for (int n=0;n<4;n++) bfr[n] = *(const bf16x8*)&Bs[cur][(wn + n*16 + rsel)*32 + kq];
#pragma unroll
    for (int m=0;m<4;m++)
#pragma unroll
      for (int n=0;n<4;n++)
        acc[m][n] = __builtin_amdgcn_mfma_f32_16x16x32_bf16(af[m], bfr[n], acc[m][n], 0, 0, 0);

    __syncthreads();
    cur ^= 1;
  }

  int cq = (lane >> 4) * 4;
  int csel = lane & 15;
#pragma unroll
  for (int m=0;m<4;m++){
#pragma unroll
    for (int n=0;n<4;n++){
#pragma unroll
      for (int j=0;j<4;j++){
        int gm = m0 + wm + m*16 + cq + j;
        int gn = n0 + wn + n*16 + csel;
        if (gm < Mvalid && gn < Nwrite){
          float v = acc[m][n][j] * scale;
          if (BIAS) v += bias[gn];
          if (GELU) v = 0.5f*v*(1.0f + erff(v*0.70710678118654752f));
          long off = cOff + (long)gm*ldc + gn;
          if (OUTF32){
            float rv = RES ? res[off] : 0.0f;
            ((float*)C)[off] = v + rv;
          } else {
            ((short*)C)[off] = f2bf(v);
          }
        }
      }
    }
  }
}

// ---------------------------------------------------------------------------
__global__ __launch_bounds__(256)
void convT(const float* __restrict__ in, short* __restrict__ out,
           int K, int N, const float* __restrict__ s)
{
  __shared__ float tile[32][33];
  int kb = blockIdx.y*32, nb = blockIdx.x*32;
  int tx = threadIdx.x & 31, ty = threadIdx.x >> 5;
  for (int i = ty; i < 32; i += 8){
    int k = kb + i, n = nb + tx;
    float v = 0.f;
    if (k < K && n < N){ v = in[(long)k*N + n]; if (s) v *= s[k]; }
    tile[i][tx] = v;
  }
  __syncthreads();
  for (int i = ty; i < 32; i += 8){
    int n = nb + i, k = kb + tx;
    if (n < N && k < K) out[(long)n*K + k] = f2bf(tile[tx][i]);
  }
}

__global__ __launch_bounds__(256)
void biasfold(const float* __restrict__ W, const float* __restrict__ bvec, float* __restrict__ outb)
{
  int n = blockIdx.x*256 + threadIdx.x;
  float s = 0.f;
  for (int k=0;k<1152;k++) s += bvec[k]*W[(long)k*3072 + n];
  outb[n] = s;
}

__global__ __launch_bounds__(256)
void cvt_bf16x4(const float* __restrict__ in, short* __restrict__ o, long n)
{
  long i = ((long)blockIdx.x*256 + threadIdx.x)*4;
  if (i >= n) return;
  float4 v = *(const float4*)(in + i);
  o[i+0]=f2bf(v.x); o[i+1]=f2bf(v.y); o[i+2]=f2bf(v.z); o[i+3]=f2bf(v.w);
}

__global__ __launch_bounds__(256)
void latcopy(const float* __restrict__ latents, float* __restrict__ lat)
{
  int idx = blockIdx.x*256 + threadIdx.x;
  int d = idx % 1152; int j = (idx / 1152) % 64; int b = idx / (1152*64);
  lat[((long)b*128 + j)*1152 + d] = latents[j*1152 + d];
}

__global__ __launch_bounds__(256)
void transV(const short* __restrict__ kv, short* __restrict__ Vt)
{
  int b = blockIdx.z;
  __shared__ short tile[32][33];
  int rb = blockIdx.y*32, cb = blockIdx.x*32;
  int tx = threadIdx.x & 31, ty = threadIdx.x >> 5;
  for (int i=ty; i<32; i+=8){
    int r = rb+i, c = cb+tx;
    short v = 0;
    if (r < 857) v = kv[((long)b*857 + r)*3072 + 1536 + c];
    tile[i][tx] = v;
  }
  __syncthreads();
  for (int i=ty;i<32;i+=8){
    int c = cb+i, r = rb+tx;
    Vt[((long)b*1536 + c)*864 + r] = tile[tx][i];
  }
}

__global__ __launch_bounds__(256)
void softmax_rows(short* __restrict__ SP)
{
  long row = (long)blockIdx.x*4 + (threadIdx.x >> 6);
  int lane = threadIdx.x & 63;
  short* p = SP + row*896;
  float vals[14];
  float mx = -1e30f;
#pragma unroll
  for (int i=0;i<14;i++){
    int j = i*64 + lane;
    float v = (j < 857) ? bf2f(p[j]) : -1e30f;
    vals[i] = v; mx = fmaxf(mx, v);
  }
#pragma unroll
  for (int o=32;o;o>>=1) mx = fmaxf(mx, __shfl_xor(mx, o));
  float s = 0.f;
#pragma unroll
  for (int i=0;i<14;i++){
    int j = i*64 + lane;
    float e = (j < 857) ? __expf(vals[i]-mx) : 0.f;
    vals[i] = e; s += e;
  }
#pragma unroll
  for (int o=32;o;o>>=1) s += __shfl_xor(s, o);
  float inv = 1.0f / s;
#pragma unroll
  for (int i=0;i<14;i++){
    int j = i*64 + lane;
    if (j < 864) p[j] = f2bf(j < 857 ? vals[i]*inv : 0.f);
  }
}

template<int OUTF32>
__global__ __launch_bounds__(256)
void ln_k(const float* __restrict__ in, void* __restrict__ outp,
          const float* __restrict__ w, const float* __restrict__ b,
          int grpSel, int grpStride)
{
  const int D = 1152;
  int r = blockIdx.x;
  long ir = (long)(r / grpSel)*grpStride + (r % grpSel);
  const float* x = in + ir*D;
  int tid = threadIdx.x;
  float s1=0.f, s2=0.f;
  float xv[5];
#pragma unroll
  for (int t=0;t<5;t++){
    int i = tid + t*256;
    xv[t] = (i < D) ? x[i] : 0.f;
    s1 += xv[t]; s2 += xv[t]*xv[t];
  }
#pragma unroll
  for (int o=32;o;o>>=1){ s1 += __shfl_xor(s1,o); s2 += __shfl_xor(s2,o); }
  __shared__ float red[8];
  int wid = tid>>6, lane = tid&63;
  if (lane==0){ red[wid]=s1; red[4+wid]=s2; }
  __syncthreads();
  s1 = red[0]+red[1]+red[2]+red[3];
  s2 = red[4]+red[5]+red[6]+red[7];
  float mu = s1 / D;
  float var = s2 / D - mu*mu;
  float rs = rsqrtf(var + 1e-5f);
#pragma unroll
  for (int t=0;t<5;t++){
    int i = tid + t*256;
    if (i >= D) break;
    float v = (xv[t]-mu)*rs;
    if (w) v = v*w[i] + b[i];
    if (OUTF32) ((float*)outp)[(long)r*D + i] = v;
    else        ((short*)outp)[(long)r*D + i] = f2bf(v);
  }
}

// ---------------------------------------------------------------------------

extern "C" void kernel_launch(void* const* d_in, const int* in_sizes, int n_in,
                              void* d_out, int out_size, void* d_ws, size_t ws_size,
                              hipStream_t stream)
{
  const float* x      = (const float*)d_in[0];
  const float* tein   = (const float*)d_in[1];
  const float* lat0   = (const float*)d_in[2];
  const float* txt_w1 = (const float*)d_in[3];
  const float* txt_b1 = (const float*)d_in[4];
  const float* txt_w2 = (const float*)d_in[5];
  const float* txt_b2 = (const float*)d_in[6];
  const float* nm_w   = (const float*)d_in[7];
  const float* nm_b   = (const float*)d_in[8];
  const float* nl_w   = (const float*)d_in[9];
  const float* nl_b   = (const float*)d_in[10];
  const float* Wq     = (const float*)d_in[11];
  const float* Wkv    = (const float*)d_in[12];
  const float* Wo     = (const float*)d_in[13];
  const float* ffln_w = (const float*)d_in[14];
  const float* ffln_b = (const float*)d_in[15];
  const float* ff_w1  = (const float*)d_in[16];
  const float* ff_w2  = (const float*)d_in[17];
  const float* oln_w  = (const float*)d_in[18];
  const float* oln_b  = (const float*)d_in[19];
  float* out = (float*)d_out;
  (void)in_sizes; (void)n_in; (void)out_size; (void)ws_size;

  char* base = (char*)d_ws;
  size_t off = 0;
  auto alloc = [&](size_t bytes)->char*{
    char* r = base + off;
    off += (bytes + 255) & ~(size_t)255;
    return r;
  };
  short* wT    = (short*)alloc(4608ULL*1152*2);
  float* biasf = (float*)alloc(3072*4);
  short* xnorm = (short*)alloc(23328ULL*1152*2);
  float* lat   = (float*)alloc(4096ULL*1152*4);
  short* lm    = (short*)alloc(4096ULL*1152*2);
  short* qb    = (short*)alloc(4096ULL*1536*2);
  short* kv    = (short*)alloc(27424ULL*3072*2);
  short* Vt    = (short*)alloc(32ULL*1536*864*2);
  short* SP    = (short*)alloc(65536ULL*896*2);
  short* attn  = (short*)alloc(4096ULL*1536*2);
  short* ffh   = (short*)alloc(4096ULL*4608*2);
  short* txtin = SP;
  short* txth  = SP + 2048ULL*4096;

  // ---- preamble ----
  cvt_bf16x4<<<8192,256,0,stream>>>(tein, txtin, 2048LL*4096);
  convT<<<dim3(36,128),256,0,stream>>>(txt_w1, wT, 4096, 1152, nullptr);
  gemm_t<1,1,0,0><<<dim3(9,16,1),256,0,stream>>>(txtin, wT, txth, txt_b1, nullptr,
      4096,4096,4096,1152, 2048,1152,1152, 1, 0,0,0,0,0,0, 1.f);
  convT<<<dim3(36,36),256,0,stream>>>(txt_w2, wT, 1152, 1152, nullptr);
  gemm_t<0,1,0,1><<<dim3(9,1,32),256,0,stream>>>(txth, wT, lat + 64*1152, txt_b2, nullptr,
      1152,1152,1152,1152, 64,1152,1152, 1, 64L*1152,0, 0,0, 128L*1152,0, 1.f);
  latcopy<<<9216,256,0,stream>>>(lat0, lat);

  ln_k<0><<<23328,256,0,stream>>>(x, xnorm, nullptr, nullptr, 1<<28, 0);

  for (int L=0; L<6; L++){
    const float* WqL  = Wq    + (size_t)L*1152*1536;
    const float* WkvL = Wkv   + (size_t)L*1152*3072;
    const float* WoL  = Wo    + (size_t)L*1536*1152;
    const float* fw1  = ff_w1 + (size_t)L*1152*4608;
    const float* fw2  = ff_w2 + (size_t)L*4608*1152;

    // lm = LN(lat; nl)
    ln_k<0><<<4096,256,0,stream>>>(lat, lm, nl_w + L*1152, nl_b + L*1152, 1<<28, 0);

    // fused q | kv-latent: wT = [Wq^T (1536 rows) ; Wkv^T (3072 rows)]
    convT<<<dim3(48,36),256,0,stream>>>(WqL, wT, 1152, 1536, nullptr);
    convT<<<dim3(96,36),256,0,stream>>>(WkvL, wT + 1536*1152, 1152, 3072, nullptr);
    gemm256<0,0,2><<<dim3(18,16),512,0,stream>>>(lm, wT, qb, kv, nullptr,
        1152,1152,1152,0, 4096, 4608, 4608);

    // kv x part (folded nm affine)
    convT<<<dim3(96,36),256,0,stream>>>(WkvL, wT, 1152, 3072, nm_w + L*1152);
    biasfold<<<12,256,0,stream>>>(WkvL, nm_b + L*1152, biasf);
    gemm256<0,1,1><<<dim3(12,92),512,0,stream>>>(xnorm, wT, kv, nullptr, biasf,
        1152,1152,1152,0, 23328, 3072, 3072);

    // Vt = V^T per batch
    transV<<<dim3(48,27,32),256,0,stream>>>(kv, Vt);

    // S = q . k^T
    gemm_t<0,0,0,0><<<dim3(7,1,512),256,0,stream>>>(qb, kv, SP, nullptr, nullptr,
        96,1536,3072,896, 128,857,896, 16,
        128L*1536,96, 857L*3072,96, 16L*128*896,128L*896, 1.f);
    softmax_rows<<<16384,256,0,stream>>>(SP);
    gemm_t<0,0,0,0><<<dim3(1,1,512),256,0,stream>>>(SP, Vt, attn, nullptr, nullptr,
        864,896,864,1536, 128,96,96, 16,
        16L*128*896,128L*896, 1536L*864,96L*864, 128L*1536,96, 1.f);

    // lat += attn @ Wo
    convT<<<dim3(36,48),256,0,stream>>>(WoL, wT, 1536, 1152, nullptr);
    gemm_t<0,0,1,1><<<dim3(9,32,1),256,0,stream>>>(attn, wT, lat, nullptr, lat,
        1536,1536,1536,1152, 4096,1152,1152, 1, 0,0,0,0,0,0, 1.f);

    // FF
    ln_k<0><<<4096,256,0,stream>>>(lat, lm, ffln_w + L*1152, ffln_b + L*1152, 1<<28, 0);
    convT<<<dim3(144,36),256,0,stream>>>(fw1, wT, 1152, 4608, nullptr);
    gemm256<1,0,0><<<dim3(18,16),512,0,stream>>>(lm, wT, ffh, nullptr, nullptr,
        1152,1152,1152,4608, 4096,4608,4608);
    convT<<<dim3(36,144),256,0,stream>>>(fw2, wT, 4608, 1152, nullptr);
    gemm_t<0,0,1,1><<<dim3(9,32,1),256,0,stream>>>(ffh, wT, lat, nullptr, lat,
        4608,4608,4608,1152, 4096,1152,1152, 1, 0,0,0,0,0,0, 1.f);
  }

  ln_k<1><<<2048,256,0,stream>>>(lat, out, oln_w, oln_b, 64, 128);
}

// Round 4
// 5890.317 us; speedup vs baseline: 1.0051x; 1.0051x over previous
//
#include <hip/hip_runtime.h>
#include <hip/hip_bf16.h>
#include <math.h>

// InstructPerceiverResampler on MI355X (gfx950).
// Round 4: gemm256 schedule cleanup vs R3:
//  - staging src pointers + LDS dest bases hoisted out of K-loop
//  - end-side sched_barrier(0) removed (mid-side kept to pin MFMA after barrier)
//  - redundant tile-boundary barrier merged (8 barriers/K-tile, was 9)
// Phase/vmcnt skeleton identical to R3 (refcheck-passed).

typedef __attribute__((ext_vector_type(4))) float f32x4;
typedef __attribute__((ext_vector_type(8))) short bf16x8;
typedef unsigned int u32;

#define DEV __device__ __forceinline__

DEV float bf2f(short s){ union{u32 u; float f;} v; v.u = ((u32)(unsigned short)s) << 16; return v.f; }
DEV short f2bf(float f){
  union{float f; u32 u;} v; v.f = f;
  u32 r = (v.u + 0x7FFFu + ((v.u >> 16) & 1u)) >> 16;
  return (short)r;
}

// ---------------------------------------------------------------------------
// 256x256 8-phase GEMM: C[m,n] = A[m,k]*B[n,k] (+bias)(+gelu), bf16 in/out.
// CMAP 0: C[gm*ldc+gn]
// CMAP 1: (kv x-part)  C[(gm/729*857 + gm%729)*3072 + gn]
// CMAP 2: (fused q|kv) gn<1536 -> C[gm*1536+gn]*SCALE ; else
//                      C2[((gm>>7)*857+729+(gm&127))*3072 + gn-1536]
// ---------------------------------------------------------------------------
template<int GELU, int BIAS, int CMAP>
__global__ __launch_bounds__(512, 2)
void gemm256(const short* __restrict__ A, const short* __restrict__ Bm,
             short* __restrict__ C, short* __restrict__ C2,
             const float* __restrict__ bias,
             int K, int lda, int ldb, int ldc,
             int Mvalid, int NBmax, int Nwrite)
{
  __shared__ __align__(16) short LDS[65536];   // 128 KiB: [buf][A(16384)|B(16384)]

  int nwg = gridDim.x * gridDim.y;
  int bid = blockIdx.y * gridDim.x + blockIdx.x;
  if ((nwg & 7) == 0){
    int chunk = nwg >> 3;
    bid = (bid & 7) * chunk + (bid >> 3);
  }
  int by = bid / gridDim.x;
  int m0 = by * 256;
  int n0 = (bid - by * gridDim.x) * 256;

  int tid = threadIdx.x;
  int lane = tid & 63;
  int w = tid >> 6;           // 0..7
  int wr = w >> 2, wc = w & 3;

  // stage constants: lane covers row (w*8 + sl), 16B-block (lane&7);
  // source col-block is (lane&7)^sl (XOR swizzle; gload_lds dest stays linear).
  int sl = lane >> 3;
  int scol = ((lane & 7) ^ sl) * 8;     // shorts

  // hoisted staging pointers: [reg][chunk], reg: 0 Blo 1 Bhi 2 Alo 3 Ahi
  const short* gsrc[4][2];
  {
    int rb = n0 + w*8 + sl;
    int ra = m0 + w*8 + sl;
    int rows[4][2] = {{rb, rb+64},{rb+128, rb+192},{ra, ra+64},{ra+128, ra+192}};
#pragma unroll
    for (int r=0;r<4;r++){
#pragma unroll
      for (int c2=0;c2<2;c2++){
        int rr = rows[r][c2];
        int lim = (r < 2) ? (NBmax-1) : (Mvalid-1);
        if (rr > lim) rr = lim;
        const short* bp = (r < 2) ? Bm : A;
        int ld = (r < 2) ? ldb : lda;
        gsrc[r][c2] = bp + (long)rr*ld + scol;
      }
    }
  }
  char* ldst[4][2];
#pragma unroll
  for (int r=0;r<4;r++){
    int sbase = ((r & 2) ? 0 : 16384) + (r & 1)*8192;   // shorts
    ldst[r][0] = (char*)LDS + (sbase + (w*8)*64)*2;
    ldst[r][1] = (char*)LDS + (sbase + (64 + w*8)*64)*2;
  }

#define GLDS(src, dst) __builtin_amdgcn_global_load_lds( \
      (const __attribute__((address_space(1))) u32*)(src), \
      (__attribute__((address_space(3))) u32*)(dst), 16, 0, 0)
#define STAGE(reg, tau) do { \
    int _bo = ((tau) & 1) ? 65536 : 0; \
    GLDS(gsrc[reg][0] + (tau)*64, ldst[reg][0] + _bo); \
    GLDS(gsrc[reg][1] + (tau)*64, ldst[reg][1] + _bo); \
  } while(0)

  // reader constants
  int rsel = lane & 15;
  int g4 = lane >> 4;
  int xr = rsel & 7;
  int blk0 = (g4 ^ xr) * 8;             // ks=0 swizzled block offset (shorts)
  int blk1 = ((4 + g4) ^ xr) * 8;       // ks=1
  int aoff = (wr*128 + rsel)*64;
  int boff = 16384 + (wc*64 + rsel)*64;

  int nt = K >> 6;

  f32x4 acc[8][4];
#pragma unroll
  for (int i=0;i<8;i++)
#pragma unroll
    for (int j=0;j<4;j++) acc[i][j] = (f32x4){0.f,0.f,0.f,0.f};

  bf16x8 a0[4], a1[4], b0[4], b1[4];
  auto ldA = [&](bf16x8* a, int mh, int blk, int bufs){
#pragma unroll
    for (int m=0;m<4;m++)
      a[m] = *(const bf16x8*)&LDS[bufs + aoff + (mh*64 + m*16)*64 + blk];
  };
  auto ldB = [&](bf16x8* bq, int blk, int bufs){
#pragma unroll
    for (int n=0;n<4;n++)
      bq[n] = *(const bf16x8*)&LDS[bufs + boff + (n*16)*64 + blk];
  };
  auto mm = [&](bf16x8* a, bf16x8* bq, int mh){
#pragma unroll
    for (int m=0;m<4;m++)
#pragma unroll
      for (int n=0;n<4;n++)
        acc[mh*4+m][n] = __builtin_amdgcn_mfma_f32_16x16x32_bf16(a[m], bq[n], acc[mh*4+m][n], 0, 0, 0);
  };

#define MID() \
    asm volatile("s_barrier" ::: "memory"); \
    __builtin_amdgcn_sched_barrier(0); \
    __builtin_amdgcn_s_setprio(1)
#define ENDP() \
    __builtin_amdgcn_s_setprio(0); \
    asm volatile("s_barrier" ::: "memory")

  // prologue: tile0 complete + tile1's B halves (6 half-tiles, 12 loads/thread)
  STAGE(0,0); STAGE(1,0); STAGE(2,0); STAGE(3,0);
  STAGE(0,1); STAGE(1,1);

#pragma unroll 1
  for (int t=0; t<nt; ++t){
    int bufs = (t & 1) * 32768;
    if (t == nt-1) { asm volatile("s_waitcnt vmcnt(0)" ::: "memory"); }
    else           { asm volatile("s_waitcnt vmcnt(4)" ::: "memory"); }
    asm volatile("s_barrier" ::: "memory");
    // P0: (mh=0, ks=0)
    ldA(a0, 0, blk0, bufs); ldB(b0, blk0, bufs);
    if (t+1 < nt) STAGE(2, t+1);
    MID(); mm(a0, b0, 0); ENDP();
    // P1: (mh=0, ks=1)
    ldA(a1, 0, blk1, bufs); ldB(b1, blk1, bufs);
    if (t+1 < nt) STAGE(3, t+1);
    MID(); mm(a1, b1, 0); ENDP();
    // P2: (mh=1, ks=0)  (b0 held in regs; B LDS region free after P1)
    ldA(a0, 1, blk0, bufs);
    if (t+2 < nt) STAGE(0, t+2);
    MID(); mm(a0, b0, 1); ENDP();
    // P3: (mh=1, ks=1)  (boundary vmcnt+barrier closes this phase)
    ldA(a1, 1, blk1, bufs);
    if (t+2 < nt) STAGE(1, t+2);
    asm volatile("s_barrier" ::: "memory");
    __builtin_amdgcn_sched_barrier(0);
    __builtin_amdgcn_s_setprio(1);
    mm(a1, b1, 1);
    __builtin_amdgcn_s_setprio(0);
  }
#undef MID
#undef ENDP
#undef STAGE
#undef GLDS

  // epilogue: C/D frag layout col=lane&15, row=(lane>>4)*4+j
  int cq = (lane >> 4) * 4;
  int csel = lane & 15;
#pragma unroll
  for (int mi=0; mi<8; mi++){
#pragma unroll
    for (int n=0; n<4; n++){
#pragma unroll
      for (int j=0; j<4; j++){
        int gm = m0 + wr*128 + mi*16 + cq + j;
        int gn = n0 + wc*64 + n*16 + csel;
        if (gm < Mvalid && gn < Nwrite){
          float v = acc[mi][n][j];
          if (BIAS) v += bias[gn];
          if (GELU) v = 0.5f*v*(1.0f + erff(v*0.70710678118654752f));
          if (CMAP == 0){
            C[(long)gm*ldc + gn] = f2bf(v);
          } else if (CMAP == 1){
            int bb = gm / 729;
            int jj = gm - bb*729;
            C[((long)bb*857 + jj)*3072 + gn] = f2bf(v);
          } else {
            if (gn < 1536){
              C[(long)gm*1536 + gn] = f2bf(v * 0.1020620726159657f);
            } else {
              int bb = gm >> 7, jj = gm & 127;
              C2[((long)bb*857 + 729 + jj)*3072 + (gn - 1536)] = f2bf(v);
            }
          }
        }
      }
    }
  }
}

// ---------------------------------------------------------------------------
// 128x128 2-phase GEMM (verified r2) for small/batched shapes.
// ---------------------------------------------------------------------------
template<int GELU, int BIAS, int RES, int OUTF32>
__global__ __launch_bounds__(256)
void gemm_t(const short* __restrict__ A, const short* __restrict__ B,
            void* __restrict__ C, const float* __restrict__ bias,
            const float* __restrict__ res,
            int K, int lda, int ldb, int ldc,
            int Mvalid, int NBmax, int Nwrite,
            int zdiv, long sA1, long sA2, long sB1, long sB2, long sC1, long sC2,
            float scale)
{
  __shared__ __align__(16) short As[2][128*32];
  __shared__ __align__(16) short Bs[2][128*32];

  int z = blockIdx.z;
  int zq = z / zdiv, zr = z - zq*zdiv;
  const short* Ab = A + zq*sA1 + zr*sA2;
  const short* Bb = B + zq*sB1 + zr*sB2;
  long cOff = zq*sC1 + zr*sC2;
  int m0 = blockIdx.y * 128;
  int n0 = blockIdx.x * 128;
  int tid = threadIdx.x;
  int lane = tid & 63;
  int w = tid >> 6;
  int wm = (w >> 1) * 64, wn = (w & 1) * 64;

  int sr = lane >> 2;
  int sc = (lane & 3) * 8;
  int ar0 = m0 + w*32 + sr;
  int br0 = n0 + w*32 + sr;

  int raA0 = ar0;      if (raA0 > Mvalid-1) raA0 = Mvalid-1;
  int raA1 = ar0 + 16; if (raA1 > Mvalid-1) raA1 = Mvalid-1;
  int rbB0 = br0;      if (rbB0 > NBmax-1) rbB0 = NBmax-1;
  int rbB1 = br0 + 16; if (rbB1 > NBmax-1) rbB1 = NBmax-1;
  const short* gA0 = Ab + (long)raA0*lda + sc;
  const short* gA1 = Ab + (long)raA1*lda + sc;
  const short* gB0 = Bb + (long)rbB0*ldb + sc;
  const short* gB1 = Bb + (long)rbB1*ldb + sc;
  int ldsRow0 = (w*32)*32;
  int ldsRow1 = (w*32 + 16)*32;

  f32x4 acc[4][4];
#pragma unroll
  for (int i=0;i<4;i++)
#pragma unroll
    for (int j=0;j<4;j++) acc[i][j] = (f32x4){0.f,0.f,0.f,0.f};

  auto stage = [&](int buf, int kb){
    __builtin_amdgcn_global_load_lds(
        (const __attribute__((address_space(1))) u32*)(gA0 + kb),
        (__attribute__((address_space(3))) u32*)(&As[buf][ldsRow0]), 16, 0, 0);
    __builtin_amdgcn_global_load_lds(
        (const __attribute__((address_space(1))) u32*)(gA1 + kb),
        (__attribute__((address_space(3))) u32*)(&As[buf][ldsRow1]), 16, 0, 0);
    __builtin_amdgcn_global_load_lds(
        (const __attribute__((address_space(1))) u32*)(gB0 + kb),
        (__attribute__((address_space(3))) u32*)(&Bs[buf][ldsRow0]), 16, 0, 0);
    __builtin_amdgcn_global_load_lds(
        (const __attribute__((address_space(1))) u32*)(gB1 + kb),
        (__attribute__((address_space(3))) u32*)(&Bs[buf][ldsRow1]), 16, 0, 0);
  };

  int nt = K >> 5;
  stage(0, 0);
  __syncthreads();

  int kq = (lane >> 4) * 8;
  int rsel = lane & 15;
  int cur = 0;
  for (int t = 0; t < nt; ++t){
    if (t + 1 < nt) stage(cur ^ 1, (t+1)*32);

    bf16x8 af[4], bfr[4];
#pragma unroll
    for (int m=0;m<4;m++) af[m]  = *(const bf16x8*)&As[cur][(wm + m*16 + rsel)*32 + kq];
#pragma unroll
    for (int n=0;n<4;n++) bfr[n] = *(const bf16x8*)&Bs[cur][(wn + n*16 + rsel)*32 + kq];
#pragma unroll
    for (int m=0;m<4;m++)
#pragma unroll
      for (int n=0;n<4;n++)
        acc[m][n] = __builtin_amdgcn_mfma_f32_16x16x32_bf16(af[m], bfr[n], acc[m][n], 0, 0, 0);

    __syncthreads();
    cur ^= 1;
  }

  int cq = (lane >> 4) * 4;
  int csel = lane & 15;
#pragma unroll
  for (int m=0;m<4;m++){
#pragma unroll
    for (int n=0;n<4;n++){
#pragma unroll
      for (int j=0;j<4;j++){
        int gm = m0 + wm + m*16 + cq + j;
        int gn = n0 + wn + n*16 + csel;
        if (gm < Mvalid && gn < Nwrite){
          float v = acc[m][n][j] * scale;
          if (BIAS) v += bias[gn];
          if (GELU) v = 0.5f*v*(1.0f + erff(v*0.70710678118654752f));
          long off = cOff + (long)gm*ldc + gn;
          if (OUTF32){
            float rv = RES ? res[off] : 0.0f;
            ((float*)C)[off] = v + rv;
          } else {
            ((short*)C)[off] = f2bf(v);
          }
        }
      }
    }
  }
}

// ---------------------------------------------------------------------------
__global__ __launch_bounds__(256)
void convT(const float* __restrict__ in, short* __restrict__ out,
           int K, int N, const float* __restrict__ s)
{
  __shared__ float tile[32][33];
  int kb = blockIdx.y*32, nb = blockIdx.x*32;
  int tx = threadIdx.x & 31, ty = threadIdx.x >> 5;
  for (int i = ty; i < 32; i += 8){
    int k = kb + i, n = nb + tx;
    float v = 0.f;
    if (k < K && n < N){ v = in[(long)k*N + n]; if (s) v *= s[k]; }
    tile[i][tx] = v;
  }
  __syncthreads();
  for (int i = ty; i < 32; i += 8){
    int n = nb + i, k = kb + tx;
    if (n < N && k < K) out[(long)n*K + k] = f2bf(tile[tx][i]);
  }
}

__global__ __launch_bounds__(256)
void biasfold(const float* __restrict__ W, const float* __restrict__ bvec, float* __restrict__ outb)
{
  int n = blockIdx.x*256 + threadIdx.x;
  float s = 0.f;
  for (int k=0;k<1152;k++) s += bvec[k]*W[(long)k*3072 + n];
  outb[n] = s;
}

__global__ __launch_bounds__(256)
void cvt_bf16x4(const float* __restrict__ in, short* __restrict__ o, long n)
{
  long i = ((long)blockIdx.x*256 + threadIdx.x)*4;
  if (i >= n) return;
  float4 v = *(const float4*)(in + i);
  o[i+0]=f2bf(v.x); o[i+1]=f2bf(v.y); o[i+2]=f2bf(v.z); o[i+3]=f2bf(v.w);
}

__global__ __launch_bounds__(256)
void latcopy(const float* __restrict__ latents, float* __restrict__ lat)
{
  int idx = blockIdx.x*256 + threadIdx.x;
  int d = idx % 1152; int j = (idx / 1152) % 64; int b = idx / (1152*64);
  lat[((long)b*128 + j)*1152 + d] = latents[j*1152 + d];
}

__global__ __launch_bounds__(256)
void transV(const short* __restrict__ kv, short* __restrict__ Vt)
{
  int b = blockIdx.z;
  __shared__ short tile[32][33];
  int rb = blockIdx.y*32, cb = blockIdx.x*32;
  int tx = threadIdx.x & 31, ty = threadIdx.x >> 5;
  for (int i=ty; i<32; i+=8){
    int r = rb+i, c = cb+tx;
    short v = 0;
    if (r < 857) v = kv[((long)b*857 + r)*3072 + 1536 + c];
    tile[i][tx] = v;
  }
  __syncthreads();
  for (int i=ty;i<32;i+=8){
    int c = cb+i, r = rb+tx;
    Vt[((long)b*1536 + c)*864 + r] = tile[tx][i];
  }
}

__global__ __launch_bounds__(256)
void softmax_rows(short* __restrict__ SP)
{
  long row = (long)blockIdx.x*4 + (threadIdx.x >> 6);
  int lane = threadIdx.x & 63;
  short* p = SP + row*896;
  float vals[14];
  float mx = -1e30f;
#pragma unroll
  for (int i=0;i<14;i++){
    int j = i*64 + lane;
    float v = (j < 857) ? bf2f(p[j]) : -1e30f;
    vals[i] = v; mx = fmaxf(mx, v);
  }
#pragma unroll
  for (int o=32;o;o>>=1) mx = fmaxf(mx, __shfl_xor(mx, o));
  float s = 0.f;
#pragma unroll
  for (int i=0;i<14;i++){
    int j = i*64 + lane;
    float e = (j < 857) ? __expf(vals[i]-mx) : 0.f;
    vals[i] = e; s += e;
  }
#pragma unroll
  for (int o=32;o;o>>=1) s += __shfl_xor(s, o);
  float inv = 1.0f / s;
#pragma unroll
  for (int i=0;i<14;i++){
    int j = i*64 + lane;
    if (j < 864) p[j] = f2bf(j < 857 ? vals[i]*inv : 0.f);
  }
}

template<int OUTF32>
__global__ __launch_bounds__(256)
void ln_k(const float* __restrict__ in, void* __restrict__ outp,
          const float* __restrict__ w, const float* __restrict__ b,
          int grpSel, int grpStride)
{
  const int D = 1152;
  int r = blockIdx.x;
  long ir = (long)(r / grpSel)*grpStride + (r % grpSel);
  const float* x = in + ir*D;
  int tid = threadIdx.x;
  float s1=0.f, s2=0.f;
  float xv[5];
#pragma unroll
  for (int t=0;t<5;t++){
    int i = tid + t*256;
    xv[t] = (i < D) ? x[i] : 0.f;
    s1 += xv[t]; s2 += xv[t]*xv[t];
  }
#pragma unroll
  for (int o=32;o;o>>=1){ s1 += __shfl_xor(s1,o); s2 += __shfl_xor(s2,o); }
  __shared__ float red[8];
  int wid = tid>>6, lane = tid&63;
  if (lane==0){ red[wid]=s1; red[4+wid]=s2; }
  __syncthreads();
  s1 = red[0]+red[1]+red[2]+red[3];
  s2 = red[4]+red[5]+red[6]+red[7];
  float mu = s1 / D;
  float var = s2 / D - mu*mu;
  float rs = rsqrtf(var + 1e-5f);
#pragma unroll
  for (int t=0;t<5;t++){
    int i = tid + t*256;
    if (i >= D) break;
    float v = (xv[t]-mu)*rs;
    if (w) v = v*w[i] + b[i];
    if (OUTF32) ((float*)outp)[(long)r*D + i] = v;
    else        ((short*)outp)[(long)r*D + i] = f2bf(v);
  }
}

// ---------------------------------------------------------------------------

extern "C" void kernel_launch(void* const* d_in, const int* in_sizes, int n_in,
                              void* d_out, int out_size, void* d_ws, size_t ws_size,
                              hipStream_t stream)
{
  const float* x      = (const float*)d_in[0];
  const float* tein   = (const float*)d_in[1];
  const float* lat0   = (const float*)d_in[2];
  const float* txt_w1 = (const float*)d_in[3];
  const float* txt_b1 = (const float*)d_in[4];
  const float* txt_w2 = (const float*)d_in[5];
  const float* txt_b2 = (const float*)d_in[6];
  const float* nm_w   = (const float*)d_in[7];
  const float* nm_b   = (const float*)d_in[8];
  const float* nl_w   = (const float*)d_in[9];
  const float* nl_b   = (const float*)d_in[10];
  const float* Wq     = (const float*)d_in[11];
  const float* Wkv    = (const float*)d_in[12];
  const float* Wo     = (const float*)d_in[13];
  const float* ffln_w = (const float*)d_in[14];
  const float* ffln_b = (const float*)d_in[15];
  const float* ff_w1  = (const float*)d_in[16];
  const float* ff_w2  = (const float*)d_in[17];
  const float* oln_w  = (const float*)d_in[18];
  const float* oln_b  = (const float*)d_in[19];
  float* out = (float*)d_out;
  (void)in_sizes; (void)n_in; (void)out_size; (void)ws_size;

  char* base = (char*)d_ws;
  size_t off = 0;
  auto alloc = [&](size_t bytes)->char*{
    char* r = base + off;
    off += (bytes + 255) & ~(size_t)255;
    return r;
  };
  short* wT    = (short*)alloc(4608ULL*1152*2);
  float* biasf = (float*)alloc(3072*4);
  short* xnorm = (short*)alloc(23328ULL*1152*2);
  float* lat   = (float*)alloc(4096ULL*1152*4);
  short* lm    = (short*)alloc(4096ULL*1152*2);
  short* qb    = (short*)alloc(4096ULL*1536*2);
  short* kv    = (short*)alloc(27424ULL*3072*2);
  short* Vt    = (short*)alloc(32ULL*1536*864*2);
  short* SP    = (short*)alloc(65536ULL*896*2);
  short* attn  = (short*)alloc(4096ULL*1536*2);
  short* ffh   = (short*)alloc(4096ULL*4608*2);
  short* txtin = SP;
  short* txth  = SP + 2048ULL*4096;

  // ---- preamble ----
  cvt_bf16x4<<<8192,256,0,stream>>>(tein, txtin, 2048LL*4096);
  convT<<<dim3(36,128),256,0,stream>>>(txt_w1, wT, 4096, 1152, nullptr);
  gemm_t<1,1,0,0><<<dim3(9,16,1),256,0,stream>>>(txtin, wT, txth, txt_b1, nullptr,
      4096,4096,4096,1152, 2048,1152,1152, 1, 0,0,0,0,0,0, 1.f);
  convT<<<dim3(36,36),256,0,stream>>>(txt_w2, wT, 1152, 1152, nullptr);
  gemm_t<0,1,0,1><<<dim3(9,1,32),256,0,stream>>>(txth, wT, lat + 64*1152, txt_b2, nullptr,
      1152,1152,1152,1152, 64,1152,1152, 1, 64L*1152,0, 0,0, 128L*1152,0, 1.f);
  latcopy<<<9216,256,0,stream>>>(lat0, lat);

  ln_k<0><<<23328,256,0,stream>>>(x, xnorm, nullptr, nullptr, 1<<28, 0);

  for (int L=0; L<6; L++){
    const float* WqL  = Wq    + (size_t)L*1152*1536;
    const float* WkvL = Wkv   + (size_t)L*1152*3072;
    const float* WoL  = Wo    + (size_t)L*1536*1152;
    const float* fw1  = ff_w1 + (size_t)L*1152*4608;
    const float* fw2  = ff_w2 + (size_t)L*4608*1152;

    // lm = LN(lat; nl)
    ln_k<0><<<4096,256,0,stream>>>(lat, lm, nl_w + L*1152, nl_b + L*1152, 1<<28, 0);

    // fused q | kv-latent: wT = [Wq^T (1536 rows) ; Wkv^T (3072 rows)]
    convT<<<dim3(48,36),256,0,stream>>>(WqL, wT, 1152, 1536, nullptr);
    convT<<<dim3(96,36),256,0,stream>>>(WkvL, wT + 1536*1152, 1152, 3072, nullptr);
    gemm256<0,0,2><<<dim3(18,16),512,0,stream>>>(lm, wT, qb, kv, nullptr,
        1152,1152,1152,0, 4096, 4608, 4608);

    // kv x part (folded nm affine)
    convT<<<dim3(96,36),256,0,stream>>>(WkvL, wT, 1152, 3072, nm_w + L*1152);
    biasfold<<<12,256,0,stream>>>(WkvL, nm_b + L*1152, biasf);
    gemm256<0,1,1><<<dim3(12,92),512,0,stream>>>(xnorm, wT, kv, nullptr, biasf,
        1152,1152,1152,0, 23328, 3072, 3072);

    // Vt = V^T per batch
    transV<<<dim3(48,27,32),256,0,stream>>>(kv, Vt);

    // S = q . k^T
    gemm_t<0,0,0,0><<<dim3(7,1,512),256,0,stream>>>(qb, kv, SP, nullptr, nullptr,
        96,1536,3072,896, 128,857,896, 16,
        128L*1536,96, 857L*3072,96, 16L*128*896,128L*896, 1.f);
    softmax_rows<<<16384,256,0,stream>>>(SP);
    gemm_t<0,0,0,0><<<dim3(1,1,512),256,0,stream>>>(SP, Vt, attn, nullptr, nullptr,
        864,896,864,1536, 128,96,96, 16,
        16L*128*896,128L*896, 1536L*864,96L*864, 128L*1536,96, 1.f);

    // lat += attn @ Wo
    convT<<<dim3(36,48),256,0,stream>>>(WoL, wT, 1536, 1152, nullptr);
    gemm_t<0,0,1,1><<<dim3(9,32,1),256,0,stream>>>(attn, wT, lat, nullptr, lat,
        1536,1536,1536,1152, 4096,1152,1152, 1, 0,0,0,0,0,0, 1.f);

    // FF
    ln_k<0><<<4096,256,0,stream>>>(lat, lm, ffln_w + L*1152, ffln_b + L*1152, 1<<28, 0);
    convT<<<dim3(144,36),256,0,stream>>>(fw1, wT, 1152, 4608, nullptr);
    gemm256<1,0,0><<<dim3(18,16),512,0,stream>>>(lm, wT, ffh, nullptr, nullptr,
        1152,1152,1152,4608, 4096,4608,4608);
    convT<<<dim3(36,144),256,0,stream>>>(fw2, wT, 4608, 1152, nullptr);
    gemm_t<0,0,1,1><<<dim3(9,32,1),256,0,stream>>>(ffh, wT, lat, nullptr, lat,
        4608,4608,4608,1152, 4096,1152,1152, 1, 0,0,0,0,0,0, 1.f);
  }

  ln_k<1><<<2048,256,0,stream>>>(lat, out, oln_w, oln_b, 64, 128);
}

// Round 5
// 5837.902 us; speedup vs baseline: 1.0141x; 1.0090x over previous
//
#include <hip/hip_runtime.h>
#include <hip/hip_bf16.h>
#include <math.h>

// InstructPerceiverResampler on MI355X (gfx950).
// Round 5: gemm256 ds_reads moved to inline-asm ds_read_b128 so the compiler
// cannot insert s_waitcnt vmcnt(0) before them (LDS-aliasing conservatism vs
// global_load_lds was draining the T4 counted-vmcnt pipeline every phase).
// Rule #18 discipline: barrier; lgkmcnt(0); sched_barrier(0); setprio(1); MFMA.
// Everything else identical to R4 (refcheck-passed, absmax 0.03125).

typedef __attribute__((ext_vector_type(4))) float f32x4;
typedef __attribute__((ext_vector_type(8))) short bf16x8;
typedef unsigned int u32;

#define DEV __device__ __forceinline__

DEV float bf2f(short s){ union{u32 u; float f;} v; v.u = ((u32)(unsigned short)s) << 16; return v.f; }
DEV short f2bf(float f){
  union{float f; u32 u;} v; v.f = f;
  u32 r = (v.u + 0x7FFFu + ((v.u >> 16) & 1u)) >> 16;
  return (short)r;
}

// LDS byte-offset of a __shared__ pointer (AS(3) pointers are 32-bit)
DEV u32 lds_off(const short* p){
  return (u32)(uintptr_t)(__attribute__((address_space(3))) const short*)p;
}
// opaque ds_read_b128 (compiler can't see the LDS dependency)
DEV bf16x8 dsr(u32 addr){
  bf16x8 r;
  asm volatile("ds_read_b128 %0, %1" : "=v"(r) : "v"(addr));
  return r;
}

// ---------------------------------------------------------------------------
// 256x256 8-phase GEMM: C[m,n] = A[m,k]*B[n,k] (+bias)(+gelu), bf16 in/out.
// CMAP 0: C[gm*ldc+gn]
// CMAP 1: (kv x-part)  C[(gm/729*857 + gm%729)*3072 + gn]
// CMAP 2: (fused q|kv) gn<1536 -> C[gm*1536+gn]*SCALE ; else
//                      C2[((gm>>7)*857+729+(gm&127))*3072 + gn-1536]
// ---------------------------------------------------------------------------
template<int GELU, int BIAS, int CMAP>
__global__ __launch_bounds__(512, 2)
void gemm256(const short* __restrict__ A, const short* __restrict__ Bm,
             short* __restrict__ C, short* __restrict__ C2,
             const float* __restrict__ bias,
             int K, int lda, int ldb, int ldc,
             int Mvalid, int NBmax, int Nwrite)
{
  __shared__ __align__(16) short LDS[65536];   // 128 KiB: [buf][A(16384)|B(16384)]

  int nwg = gridDim.x * gridDim.y;
  int bid = blockIdx.y * gridDim.x + blockIdx.x;
  if ((nwg & 7) == 0){
    int chunk = nwg >> 3;
    bid = (bid & 7) * chunk + (bid >> 3);
  }
  int by = bid / gridDim.x;
  int m0 = by * 256;
  int n0 = (bid - by * gridDim.x) * 256;

  int tid = threadIdx.x;
  int lane = tid & 63;
  int w = tid >> 6;           // 0..7
  int wr = w >> 2, wc = w & 3;

  // stage constants: lane covers row (w*8 + sl), 16B-block (lane&7);
  // source col-block is (lane&7)^sl (XOR swizzle; gload_lds dest stays linear).
  int sl = lane >> 3;
  int scol = ((lane & 7) ^ sl) * 8;     // shorts

  // hoisted staging pointers: [reg][chunk], reg: 0 Blo 1 Bhi 2 Alo 3 Ahi
  const short* gsrc[4][2];
  {
    int rb = n0 + w*8 + sl;
    int ra = m0 + w*8 + sl;
    int rows[4][2] = {{rb, rb+64},{rb+128, rb+192},{ra, ra+64},{ra+128, ra+192}};
#pragma unroll
    for (int r=0;r<4;r++){
#pragma unroll
      for (int c2=0;c2<2;c2++){
        int rr = rows[r][c2];
        int lim = (r < 2) ? (NBmax-1) : (Mvalid-1);
        if (rr > lim) rr = lim;
        const short* bp = (r < 2) ? Bm : A;
        int ld = (r < 2) ? ldb : lda;
        gsrc[r][c2] = bp + (long)rr*ld + scol;
      }
    }
  }
  char* ldst[4][2];
#pragma unroll
  for (int r=0;r<4;r++){
    int sbase = ((r & 2) ? 0 : 16384) + (r & 1)*8192;   // shorts
    ldst[r][0] = (char*)LDS + (sbase + (w*8)*64)*2;
    ldst[r][1] = (char*)LDS + (sbase + (64 + w*8)*64)*2;
  }

#define GLDS(src, dst) __builtin_amdgcn_global_load_lds( \
      (const __attribute__((address_space(1))) u32*)(src), \
      (__attribute__((address_space(3))) u32*)(dst), 16, 0, 0)
#define STAGE(reg, tau) do { \
    int _bo = ((tau) & 1) ? 65536 : 0; \
    GLDS(gsrc[reg][0] + (tau)*64, ldst[reg][0] + _bo); \
    GLDS(gsrc[reg][1] + (tau)*64, ldst[reg][1] + _bo); \
  } while(0)

  // reader constants (byte offsets for asm ds_read)
  int rsel = lane & 15;
  int g4 = lane >> 4;
  int xr = rsel & 7;
  u32 blk0 = (u32)((g4 ^ xr) * 16);            // ks=0 swizzled block (bytes)
  u32 blk1 = (u32)(((4 + g4) ^ xr) * 16);      // ks=1
  u32 aA = lds_off(LDS) + (u32)((wr*128 + rsel)*128);            // A row base
  u32 bB = lds_off(LDS) + 32768u + (u32)((wc*64 + rsel)*128);    // B row base

  int nt = K >> 6;

  f32x4 acc[8][4];
#pragma unroll
  for (int i=0;i<8;i++)
#pragma unroll
    for (int j=0;j<4;j++) acc[i][j] = (f32x4){0.f,0.f,0.f,0.f};

  bf16x8 a0[4], a1[4], b0[4], b1[4];
  auto ldA = [&](bf16x8* a, int mh, u32 blkB, u32 bufo){
#pragma unroll
    for (int m=0;m<4;m++)
      a[m] = dsr(aA + bufo + (u32)((mh*64 + m*16)*128) + blkB);
  };
  auto ldB = [&](bf16x8* bq, u32 blkB, u32 bufo){
#pragma unroll
    for (int n=0;n<4;n++)
      bq[n] = dsr(bB + bufo + (u32)((n*16)*128) + blkB);
  };
  auto mm = [&](bf16x8* a, bf16x8* bq, int mh){
#pragma unroll
    for (int m=0;m<4;m++)
#pragma unroll
      for (int n=0;n<4;n++)
        acc[mh*4+m][n] = __builtin_amdgcn_mfma_f32_16x16x32_bf16(a[m], bq[n], acc[mh*4+m][n], 0, 0, 0);
  };

#define MID() \
    asm volatile("s_barrier" ::: "memory"); \
    asm volatile("s_waitcnt lgkmcnt(0)" ::: "memory"); \
    __builtin_amdgcn_sched_barrier(0); \
    __builtin_amdgcn_s_setprio(1)
#define ENDP() \
    __builtin_amdgcn_s_setprio(0); \
    asm volatile("s_barrier" ::: "memory")

  // prologue: tile0 complete + tile1's B halves (6 half-tiles, 12 loads/thread)
  STAGE(0,0); STAGE(1,0); STAGE(2,0); STAGE(3,0);
  STAGE(0,1); STAGE(1,1);

#pragma unroll 1
  for (int t=0; t<nt; ++t){
    u32 bufo = (u32)(t & 1) * 65536u;
    if (t == nt-1) { asm volatile("s_waitcnt vmcnt(0)" ::: "memory"); }
    else           { asm volatile("s_waitcnt vmcnt(4)" ::: "memory"); }
    asm volatile("s_barrier" ::: "memory");
    // P0: (mh=0, ks=0)
    ldA(a0, 0, blk0, bufo); ldB(b0, blk0, bufo);
    if (t+1 < nt) STAGE(2, t+1);
    MID(); mm(a0, b0, 0); ENDP();
    // P1: (mh=0, ks=1)
    ldA(a1, 0, blk1, bufo); ldB(b1, blk1, bufo);
    if (t+1 < nt) STAGE(3, t+1);
    MID(); mm(a1, b1, 0); ENDP();
    // P2: (mh=1, ks=0)  (b0 held in regs; B-lo writes for t+2 issue after P1's
    //                    readers completed at P1-mid lgkmcnt -> safe)
    ldA(a0, 1, blk0, bufo);
    if (t+2 < nt) STAGE(0, t+2);
    MID(); mm(a0, b0, 1); ENDP();
    // P3: (mh=1, ks=1)  (tile-boundary vmcnt+barrier closes this phase)
    ldA(a1, 1, blk1, bufo);
    if (t+2 < nt) STAGE(1, t+2);
    MID(); mm(a1, b1, 1);
    __builtin_amdgcn_s_setprio(0);
  }
#undef MID
#undef ENDP
#undef STAGE
#undef GLDS

  // epilogue: C/D frag layout col=lane&15, row=(lane>>4)*4+j
  int cq = (lane >> 4) * 4;
  int csel = lane & 15;
#pragma unroll
  for (int mi=0; mi<8; mi++){
#pragma unroll
    for (int n=0; n<4; n++){
#pragma unroll
      for (int j=0; j<4; j++){
        int gm = m0 + wr*128 + mi*16 + cq + j;
        int gn = n0 + wc*64 + n*16 + csel;
        if (gm < Mvalid && gn < Nwrite){
          float v = acc[mi][n][j];
          if (BIAS) v += bias[gn];
          if (GELU) v = 0.5f*v*(1.0f + erff(v*0.70710678118654752f));
          if (CMAP == 0){
            C[(long)gm*ldc + gn] = f2bf(v);
          } else if (CMAP == 1){
            int bb = gm / 729;
            int jj = gm - bb*729;
            C[((long)bb*857 + jj)*3072 + gn] = f2bf(v);
          } else {
            if (gn < 1536){
              C[(long)gm*1536 + gn] = f2bf(v * 0.1020620726159657f);
            } else {
              int bb = gm >> 7, jj = gm & 127;
              C2[((long)bb*857 + 729 + jj)*3072 + (gn - 1536)] = f2bf(v);
            }
          }
        }
      }
    }
  }
}

// ---------------------------------------------------------------------------
// 128x128 2-phase GEMM (verified r2) for small/batched shapes.
// ---------------------------------------------------------------------------
template<int GELU, int BIAS, int RES, int OUTF32>
__global__ __launch_bounds__(256)
void gemm_t(const short* __restrict__ A, const short* __restrict__ B,
            void* __restrict__ C, const float* __restrict__ bias,
            const float* __restrict__ res,
            int K, int lda, int ldb, int ldc,
            int Mvalid, int NBmax, int Nwrite,
            int zdiv, long sA1, long sA2, long sB1, long sB2, long sC1, long sC2,
            float scale)
{
  __shared__ __align__(16) short As[2][128*32];
  __shared__ __align__(16) short Bs[2][128*32];

  int z = blockIdx.z;
  int zq = z / zdiv, zr = z - zq*zdiv;
  const short* Ab = A + zq*sA1 + zr*sA2;
  const short* Bb = B + zq*sB1 + zr*sB2;
  long cOff = zq*sC1 + zr*sC2;
  int m0 = blockIdx.y * 128;
  int n0 = blockIdx.x * 128;
  int tid = threadIdx.x;
  int lane = tid & 63;
  int w = tid >> 6;
  int wm = (w >> 1) * 64, wn = (w & 1) * 64;

  int sr = lane >> 2;
  int sc = (lane & 3) * 8;
  int ar0 = m0 + w*32 + sr;
  int br0 = n0 + w*32 + sr;

  int raA0 = ar0;      if (raA0 > Mvalid-1) raA0 = Mvalid-1;
  int raA1 = ar0 + 16; if (raA1 > Mvalid-1) raA1 = Mvalid-1;
  int rbB0 = br0;      if (rbB0 > NBmax-1) rbB0 = NBmax-1;
  int rbB1 = br0 + 16; if (rbB1 > NBmax-1) rbB1 = NBmax-1;
  const short* gA0 = Ab + (long)raA0*lda + sc;
  const short* gA1 = Ab + (long)raA1*lda + sc;
  const short* gB0 = Bb + (long)rbB0*ldb + sc;
  const short* gB1 = Bb + (long)rbB1*ldb + sc;
  int ldsRow0 = (w*32)*32;
  int ldsRow1 = (w*32 + 16)*32;

  f32x4 acc[4][4];
#pragma unroll
  for (int i=0;i<4;i++)
#pragma unroll
    for (int j=0;j<4;j++) acc[i][j] = (f32x4){0.f,0.f,0.f,0.f};

  auto stage = [&](int buf, int kb){
    __builtin_amdgcn_global_load_lds(
        (const __attribute__((address_space(1))) u32*)(gA0 + kb),
        (__attribute__((address_space(3))) u32*)(&As[buf][ldsRow0]), 16, 0, 0);
    __builtin_amdgcn_global_load_lds(
        (const __attribute__((address_space(1))) u32*)(gA1 + kb),
        (__attribute__((address_space(3))) u32*)(&As[buf][ldsRow1]), 16, 0, 0);
    __builtin_amdgcn_global_load_lds(
        (const __attribute__((address_space(1))) u32*)(gB0 + kb),
        (__attribute__((address_space(3))) u32*)(&Bs[buf][ldsRow0]), 16, 0, 0);
    __builtin_amdgcn_global_load_lds(
        (const __attribute__((address_space(1))) u32*)(gB1 + kb),
        (__attribute__((address_space(3))) u32*)(&Bs[buf][ldsRow1]), 16, 0, 0);
  };

  int nt = K >> 5;
  stage(0, 0);
  __syncthreads();

  int kq = (lane >> 4) * 8;
  int rsel = lane & 15;
  int cur = 0;
  for (int t = 0; t < nt; ++t){
    if (t + 1 < nt) stage(cur ^ 1, (t+1)*32);

    bf16x8 af[4], bfr[4];
#pragma unroll
    for (int m=0;m<4;m++) af[m]  = *(const bf16x8*)&As[cur][(wm + m*16 + rsel)*32 + kq];
#pragma unroll
    for (int n=0;n<4;n++) bfr[n] = *(const bf16x8*)&Bs[cur][(wn + n*16 + rsel)*32 + kq];
#pragma unroll
    for (int m=0;m<4;m++)
#pragma unroll
      for (int n=0;n<4;n++)
        acc[m][n] = __builtin_amdgcn_mfma_f32_16x16x32_bf16(af[m], bfr[n], acc[m][n], 0, 0, 0);

    __syncthreads();
    cur ^= 1;
  }

  int cq = (lane >> 4) * 4;
  int csel = lane & 15;
#pragma unroll
  for (int m=0;m<4;m++){
#pragma unroll
    for (int n=0;n<4;n++){
#pragma unroll
      for (int j=0;j<4;j++){
        int gm = m0 + wm + m*16 + cq + j;
        int gn = n0 + wn + n*16 + csel;
        if (gm < Mvalid && gn < Nwrite){
          float v = acc[m][n][j] * scale;
          if (BIAS) v += bias[gn];
          if (GELU) v = 0.5f*v*(1.0f + erff(v*0.70710678118654752f));
          long off = cOff + (long)gm*ldc + gn;
          if (OUTF32){
            float rv = RES ? res[off] : 0.0f;
            ((float*)C)[off] = v + rv;
          } else {
            ((short*)C)[off] = f2bf(v);
          }
        }
      }
    }
  }
}

// ---------------------------------------------------------------------------
__global__ __launch_bounds__(256)
void convT(const float* __restrict__ in, short* __restrict__ out,
           int K, int N, const float* __restrict__ s)
{
  __shared__ float tile[32][33];
  int kb = blockIdx.y*32, nb = blockIdx.x*32;
  int tx = threadIdx.x & 31, ty = threadIdx.x >> 5;
  for (int i = ty; i < 32; i += 8){
    int k = kb + i, n = nb + tx;
    float v = 0.f;
    if (k < K && n < N){ v = in[(long)k*N + n]; if (s) v *= s[k]; }
    tile[i][tx] = v;
  }
  __syncthreads();
  for (int i = ty; i < 32; i += 8){
    int n = nb + i, k = kb + tx;
    if (n < N && k < K) out[(long)n*K + k] = f2bf(tile[tx][i]);
  }
}

__global__ __launch_bounds__(256)
void biasfold(const float* __restrict__ W, const float* __restrict__ bvec, float* __restrict__ outb)
{
  int n = blockIdx.x*256 + threadIdx.x;
  float s = 0.f;
  for (int k=0;k<1152;k++) s += bvec[k]*W[(long)k*3072 + n];
  outb[n] = s;
}

__global__ __launch_bounds__(256)
void cvt_bf16x4(const float* __restrict__ in, short* __restrict__ o, long n)
{
  long i = ((long)blockIdx.x*256 + threadIdx.x)*4;
  if (i >= n) return;
  float4 v = *(const float4*)(in + i);
  o[i+0]=f2bf(v.x); o[i+1]=f2bf(v.y); o[i+2]=f2bf(v.z); o[i+3]=f2bf(v.w);
}

__global__ __launch_bounds__(256)
void latcopy(const float* __restrict__ latents, float* __restrict__ lat)
{
  int idx = blockIdx.x*256 + threadIdx.x;
  int d = idx % 1152; int j = (idx / 1152) % 64; int b = idx / (1152*64);
  lat[((long)b*128 + j)*1152 + d] = latents[j*1152 + d];
}

__global__ __launch_bounds__(256)
void transV(const short* __restrict__ kv, short* __restrict__ Vt)
{
  int b = blockIdx.z;
  __shared__ short tile[32][33];
  int rb = blockIdx.y*32, cb = blockIdx.x*32;
  int tx = threadIdx.x & 31, ty = threadIdx.x >> 5;
  for (int i=ty; i<32; i+=8){
    int r = rb+i, c = cb+tx;
    short v = 0;
    if (r < 857) v = kv[((long)b*857 + r)*3072 + 1536 + c];
    tile[i][tx] = v;
  }
  __syncthreads();
  for (int i=ty;i<32;i+=8){
    int c = cb+i, r = rb+tx;
    Vt[((long)b*1536 + c)*864 + r] = tile[tx][i];
  }
}

__global__ __launch_bounds__(256)
void softmax_rows(short* __restrict__ SP)
{
  long row = (long)blockIdx.x*4 + (threadIdx.x >> 6);
  int lane = threadIdx.x & 63;
  short* p = SP + row*896;
  float vals[14];
  float mx = -1e30f;
#pragma unroll
  for (int i=0;i<14;i++){
    int j = i*64 + lane;
    float v = (j < 857) ? bf2f(p[j]) : -1e30f;
    vals[i] = v; mx = fmaxf(mx, v);
  }
#pragma unroll
  for (int o=32;o;o>>=1) mx = fmaxf(mx, __shfl_xor(mx, o));
  float s = 0.f;
#pragma unroll
  for (int i=0;i<14;i++){
    int j = i*64 + lane;
    float e = (j < 857) ? __expf(vals[i]-mx) : 0.f;
    vals[i] = e; s += e;
  }
#pragma unroll
  for (int o=32;o;o>>=1) s += __shfl_xor(s, o);
  float inv = 1.0f / s;
#pragma unroll
  for (int i=0;i<14;i++){
    int j = i*64 + lane;
    if (j < 864) p[j] = f2bf(j < 857 ? vals[i]*inv : 0.f);
  }
}

template<int OUTF32>
__global__ __launch_bounds__(256)
void ln_k(const float* __restrict__ in, void* __restrict__ outp,
          const float* __restrict__ w, const float* __restrict__ b,
          int grpSel, int grpStride)
{
  const int D = 1152;
  int r = blockIdx.x;
  long ir = (long)(r / grpSel)*grpStride + (r % grpSel);
  const float* x = in + ir*D;
  int tid = threadIdx.x;
  float s1=0.f, s2=0.f;
  float xv[5];
#pragma unroll
  for (int t=0;t<5;t++){
    int i = tid + t*256;
    xv[t] = (i < D) ? x[i] : 0.f;
    s1 += xv[t]; s2 += xv[t]*xv[t];
  }
#pragma unroll
  for (int o=32;o;o>>=1){ s1 += __shfl_xor(s1,o); s2 += __shfl_xor(s2,o); }
  __shared__ float red[8];
  int wid = tid>>6, lane = tid&63;
  if (lane==0){ red[wid]=s1; red[4+wid]=s2; }
  __syncthreads();
  s1 = red[0]+red[1]+red[2]+red[3];
  s2 = red[4]+red[5]+red[6]+red[7];
  float mu = s1 / D;
  float var = s2 / D - mu*mu;
  float rs = rsqrtf(var + 1e-5f);
#pragma unroll
  for (int t=0;t<5;t++){
    int i = tid + t*256;
    if (i >= D) break;
    float v = (xv[t]-mu)*rs;
    if (w) v = v*w[i] + b[i];
    if (OUTF32) ((float*)outp)[(long)r*D + i] = v;
    else        ((short*)outp)[(long)r*D + i] = f2bf(v);
  }
}

// ---------------------------------------------------------------------------

extern "C" void kernel_launch(void* const* d_in, const int* in_sizes, int n_in,
                              void* d_out, int out_size, void* d_ws, size_t ws_size,
                              hipStream_t stream)
{
  const float* x      = (const float*)d_in[0];
  const float* tein   = (const float*)d_in[1];
  const float* lat0   = (const float*)d_in[2];
  const float* txt_w1 = (const float*)d_in[3];
  const float* txt_b1 = (const float*)d_in[4];
  const float* txt_w2 = (const float*)d_in[5];
  const float* txt_b2 = (const float*)d_in[6];
  const float* nm_w   = (const float*)d_in[7];
  const float* nm_b   = (const float*)d_in[8];
  const float* nl_w   = (const float*)d_in[9];
  const float* nl_b   = (const float*)d_in[10];
  const float* Wq     = (const float*)d_in[11];
  const float* Wkv    = (const float*)d_in[12];
  const float* Wo     = (const float*)d_in[13];
  const float* ffln_w = (const float*)d_in[14];
  const float* ffln_b = (const float*)d_in[15];
  const float* ff_w1  = (const float*)d_in[16];
  const float* ff_w2  = (const float*)d_in[17];
  const float* oln_w  = (const float*)d_in[18];
  const float* oln_b  = (const float*)d_in[19];
  float* out = (float*)d_out;
  (void)in_sizes; (void)n_in; (void)out_size; (void)ws_size;

  char* base = (char*)d_ws;
  size_t off = 0;
  auto alloc = [&](size_t bytes)->char*{
    char* r = base + off;
    off += (bytes + 255) & ~(size_t)255;
    return r;
  };
  short* wT    = (short*)alloc(4608ULL*1152*2);
  float* biasf = (float*)alloc(3072*4);
  short* xnorm = (short*)alloc(23328ULL*1152*2);
  float* lat   = (float*)alloc(4096ULL*1152*4);
  short* lm    = (short*)alloc(4096ULL*1152*2);
  short* qb    = (short*)alloc(4096ULL*1536*2);
  short* kv    = (short*)alloc(27424ULL*3072*2);
  short* Vt    = (short*)alloc(32ULL*1536*864*2);
  short* SP    = (short*)alloc(65536ULL*896*2);
  short* attn  = (short*)alloc(4096ULL*1536*2);
  short* ffh   = (short*)alloc(4096ULL*4608*2);
  short* txtin = SP;
  short* txth  = SP + 2048ULL*4096;

  // ---- preamble ----
  cvt_bf16x4<<<8192,256,0,stream>>>(tein, txtin, 2048LL*4096);
  convT<<<dim3(36,128),256,0,stream>>>(txt_w1, wT, 4096, 1152, nullptr);
  gemm_t<1,1,0,0><<<dim3(9,16,1),256,0,stream>>>(txtin, wT, txth, txt_b1, nullptr,
      4096,4096,4096,1152, 2048,1152,1152, 1, 0,0,0,0,0,0, 1.f);
  convT<<<dim3(36,36),256,0,stream>>>(txt_w2, wT, 1152, 1152, nullptr);
  gemm_t<0,1,0,1><<<dim3(9,1,32),256,0,stream>>>(txth, wT, lat + 64*1152, txt_b2, nullptr,
      1152,1152,1152,1152, 64,1152,1152, 1, 64L*1152,0, 0,0, 128L*1152,0, 1.f);
  latcopy<<<9216,256,0,stream>>>(lat0, lat);

  ln_k<0><<<23328,256,0,stream>>>(x, xnorm, nullptr, nullptr, 1<<28, 0);

  for (int L=0; L<6; L++){
    const float* WqL  = Wq    + (size_t)L*1152*1536;
    const float* WkvL = Wkv   + (size_t)L*1152*3072;
    const float* WoL  = Wo    + (size_t)L*1536*1152;
    const float* fw1  = ff_w1 + (size_t)L*1152*4608;
    const float* fw2  = ff_w2 + (size_t)L*4608*1152;

    // lm = LN(lat; nl)
    ln_k<0><<<4096,256,0,stream>>>(lat, lm, nl_w + L*1152, nl_b + L*1152, 1<<28, 0);

    // fused q | kv-latent: wT = [Wq^T (1536 rows) ; Wkv^T (3072 rows)]
    convT<<<dim3(48,36),256,0,stream>>>(WqL, wT, 1152, 1536, nullptr);
    convT<<<dim3(96,36),256,0,stream>>>(WkvL, wT + 1536*1152, 1152, 3072, nullptr);
    gemm256<0,0,2><<<dim3(18,16),512,0,stream>>>(lm, wT, qb, kv, nullptr,
        1152,1152,1152,0, 4096, 4608, 4608);

    // kv x part (folded nm affine)
    convT<<<dim3(96,36),256,0,stream>>>(WkvL, wT, 1152, 3072, nm_w + L*1152);
    biasfold<<<12,256,0,stream>>>(WkvL, nm_b + L*1152, biasf);
    gemm256<0,1,1><<<dim3(12,92),512,0,stream>>>(xnorm, wT, kv, nullptr, biasf,
        1152,1152,1152,0, 23328, 3072, 3072);

    // Vt = V^T per batch
    transV<<<dim3(48,27,32),256,0,stream>>>(kv, Vt);

    // S = q . k^T
    gemm_t<0,0,0,0><<<dim3(7,1,512),256,0,stream>>>(qb, kv, SP, nullptr, nullptr,
        96,1536,3072,896, 128,857,896, 16,
        128L*1536,96, 857L*3072,96, 16L*128*896,128L*896, 1.f);
    softmax_rows<<<16384,256,0,stream>>>(SP);
    gemm_t<0,0,0,0><<<dim3(1,1,512),256,0,stream>>>(SP, Vt, attn, nullptr, nullptr,
        864,896,864,1536, 128,96,96, 16,
        16L*128*896,128L*896, 1536L*864,96L*864, 128L*1536,96, 1.f);

    // lat += attn @ Wo
    convT<<<dim3(36,48),256,0,stream>>>(WoL, wT, 1536, 1152, nullptr);
    gemm_t<0,0,1,1><<<dim3(9,32,1),256,0,stream>>>(attn, wT, lat, nullptr, lat,
        1536,1536,1536,1152, 4096,1152,1152, 1, 0,0,0,0,0,0, 1.f);

    // FF
    ln_k<0><<<4096,256,0,stream>>>(lat, lm, ffln_w + L*1152, ffln_b + L*1152, 1<<28, 0);
    convT<<<dim3(144,36),256,0,stream>>>(fw1, wT, 1152, 4608, nullptr);
    gemm256<1,0,0><<<dim3(18,16),512,0,stream>>>(lm, wT, ffh, nullptr, nullptr,
        1152,1152,1152,4608, 4096,4608,4608);
    convT<<<dim3(36,144),256,0,stream>>>(fw2, wT, 4608, 1152, nullptr);
    gemm_t<0,0,1,1><<<dim3(9,32,1),256,0,stream>>>(ffh, wT, lat, nullptr, lat,
        4608,4608,4608,1152, 4096,1152,1152, 1, 0,0,0,0,0,0, 1.f);
  }

  ln_k<1><<<2048,256,0,stream>>>(lat, out, oln_w, oln_b, 64, 128);
}